// Round 2
// baseline (110.624 us; speedup 1.0000x reference)
//
#include <hip/hip_runtime.h>
#include <float.h>

#define B_ 4
#define C_ 128
#define H_ 128
#define W_ 128
#define WL_ 32
#define NL_ 1024   // 32*32 low-res cells

// ---------------------------------------------------------------------------
// Kernel 1: 4x4 block sums. S[b][cell][c] (fp32), cell = cr*32 + cc.
// One block per (b,c) plane; float4 (16B) coalesced loads.
// ---------------------------------------------------------------------------
__global__ __launch_bounds__(256) void k_blocksum(const float* __restrict__ v,
                                                  float* __restrict__ S) {
    int plane = blockIdx.x;          // b*C + c
    int b = plane >> 7;
    int c = plane & 127;
    const float* vp = v + (size_t)plane * (H_ * W_);
    int tid = threadIdx.x;
    #pragma unroll
    for (int rep = 0; rep < 4; ++rep) {
        int cell = rep * 256 + tid;          // 0..1023
        int cr = cell >> 5, cc = cell & 31;
        const float* rp = vp + (cr * 4) * W_ + cc * 4;
        float s = 0.f;
        #pragma unroll
        for (int r = 0; r < 4; ++r) {
            float4 u = *(const float4*)(rp + r * W_);
            s += u.x + u.y + u.z + u.w;
        }
        S[((size_t)b * NL_ + cell) * C_ + c] = s;
    }
}

// ---------------------------------------------------------------------------
// Kernel 2a: stable top-2 + 2-way softmax per attention row.
// One wave (64 lanes) per row; float4 loads (per-lane indices strictly
// increasing => plain '>' gives jax.lax.top_k's lowest-index-on-tie).
// ---------------------------------------------------------------------------
__global__ __launch_bounds__(256) void k_topk(const float* __restrict__ attn,
                                              int2* __restrict__ tmap,
                                              float2* __restrict__ wmap) {
    int lane = threadIdx.x & 63;
    int wv   = threadIdx.x >> 6;
    int row  = blockIdx.x * 4 + wv;      // 0..4095  (b*1024 + q)
    const float4* p = (const float4*)(attn + (size_t)row * NL_);

    float v0 = -FLT_MAX, v1 = -FLT_MAX;
    int   i0 = 0x7fffffff, i1 = 0x7fffffff;

    #pragma unroll
    for (int s = 0; s < 4; ++s) {
        float4 u = p[lane + 64 * s];
        int j = 4 * (lane + 64 * s);
        float vals[4] = {u.x, u.y, u.z, u.w};
        #pragma unroll
        for (int t = 0; t < 4; ++t) {
            float a = vals[t];
            int   ji = j + t;
            if (a > v0)      { v1 = v0; i1 = i0; v0 = a; i0 = ji; }
            else if (a > v1) { v1 = a; i1 = ji; }
        }
    }

    #pragma unroll
    for (int off = 32; off >= 1; off >>= 1) {
        float ov0 = __shfl_xor(v0, off, 64);
        int   oi0 = __shfl_xor(i0, off, 64);
        float ov1 = __shfl_xor(v1, off, 64);
        int   oi1 = __shfl_xor(i1, off, 64);
        bool a_first = (v0 > ov0) || (v0 == ov0 && i0 < oi0);
        float n0, n1; int m0, m1;
        if (a_first) {
            n0 = v0; m0 = i0;
            bool s2 = (v1 > ov0) || (v1 == ov0 && i1 < oi0);
            n1 = s2 ? v1 : ov0; m1 = s2 ? i1 : oi0;
        } else {
            n0 = ov0; m0 = oi0;
            bool s2 = (v0 > ov1) || (v0 == ov1 && i0 < oi1);
            n1 = s2 ? v0 : ov1; m1 = s2 ? i0 : oi1;
        }
        v0 = n0; i0 = m0; v1 = n1; i1 = m1;
    }

    if (lane == 0) {
        float e  = expf(v1 - v0);        // v1 <= v0, safe
        float w0 = 1.f / (1.f + e);
        tmap[row] = make_int2(i0, i1);
        wmap[row] = make_float2(w0, 1.f - w0);
    }
}

// ---------------------------------------------------------------------------
// Kernel 2b: combine + write. Output is constant over each 4x4 tile, so each
// thread computes one value and stores 4 fp32 pixels (16B coalesced store).
// ---------------------------------------------------------------------------
__global__ __launch_bounds__(256) void k_out(const float* __restrict__ S,
                                             const int2* __restrict__ tmap,
                                             const float2* __restrict__ wmap,
                                             float* __restrict__ out) {
    int tid = blockIdx.x * 256 + threadIdx.x;   // 0 .. 2*1024*1024-1
    int wb = tid & 31;            // cell column
    int h  = (tid >> 5) & 127;    // output row
    int c  = (tid >> 12) & 127;
    int b  = tid >> 19;
    int q  = (h >> 2) * WL_ + wb;
    int row = b * NL_ + q;

    int2   t = tmap[row];
    float2 w = wmap[row];
    const float* Sb = S + (size_t)b * NL_ * C_;
    float s0 = Sb[(size_t)t.x * C_ + c];
    float s1 = Sb[(size_t)t.y * C_ + c];
    float val = (w.x * s0 + w.y * s1) * 0.0625f;   // /16

    float4 o4 = make_float4(val, val, val, val);
    *(float4*)(out + ((size_t)(b * C_ + c) * H_ + h) * W_ + wb * 4) = o4;
}

extern "C" void kernel_launch(void* const* d_in, const int* in_sizes, int n_in,
                              void* d_out, int out_size, void* d_ws, size_t ws_size,
                              hipStream_t stream) {
    const float* v    = (const float*)d_in[0];   // fp32 (B,C,H,W)
    const float* attn = (const float*)d_in[1];   // fp32 (B,1024,1024)
    float* out = (float*)d_out;                  // fp32 (B,C,H,W)

    char* base = (char*)d_ws;
    float*  S    = (float*)base;                                   // 2 MB
    int2*   tmap = (int2*)(base + (size_t)B_ * NL_ * C_ * 4);      // 32 KB
    float2* wmap = (float2*)(base + (size_t)B_ * NL_ * C_ * 4 + 4096 * sizeof(int2));

    k_blocksum<<<B_ * C_, 256, 0, stream>>>(v, S);
    k_topk<<<1024, 256, 0, stream>>>(attn, tmap, wmap);
    k_out<<<(B_ * C_ * H_ * WL_) / 256, 256, 0, stream>>>(S, tmap, wmap, out);
}

// Round 3
// 100.997 us; speedup vs baseline: 1.0953x; 1.0953x over previous
//
#include <hip/hip_runtime.h>
#include <float.h>

#define B_ 4
#define C_ 128
#define H_ 128
#define W_ 128
#define WL_ 32
#define NL_ 1024   // 32*32 low-res cells

// ---------------------------------------------------------------------------
// Kernel A: fused block-sum + top-2.
//   blocks [0, 512):    4x4 block sums -> S_t[b][c][cell]  (transposed layout:
//                       lane-consecutive cells => fully coalesced 4B writes,
//                       full 64B sectors, single-XCD ownership per 4KB slice)
//   blocks [512, 1536): stable top-2 + 2-way softmax per attention row
// ---------------------------------------------------------------------------
__global__ __launch_bounds__(256) void k_fusedA(const float* __restrict__ v,
                                                const float* __restrict__ attn,
                                                float* __restrict__ S,
                                                int2* __restrict__ tmap,
                                                float2* __restrict__ wmap) {
    if (blockIdx.x < 512) {
        // ---- block-sum section: one block per (b,c) plane ----
        int plane = blockIdx.x;          // b*C + c
        const float* vp = v + (size_t)plane * (H_ * W_);
        float* Sp = S + (size_t)plane * NL_;
        int tid = threadIdx.x;
        #pragma unroll
        for (int rep = 0; rep < 4; ++rep) {
            int cell = rep * 256 + tid;          // 0..1023
            int cr = cell >> 5, cc = cell & 31;
            const float* rp = vp + (cr * 4) * W_ + cc * 4;
            float s = 0.f;
            #pragma unroll
            for (int r = 0; r < 4; ++r) {
                float4 u = *(const float4*)(rp + r * W_);
                s += u.x + u.y + u.z + u.w;
            }
            Sp[cell] = s;                        // coalesced: lanes -> cells
        }
    } else {
        // ---- top-2 section: one wave per attention row ----
        int lane = threadIdx.x & 63;
        int wv   = threadIdx.x >> 6;
        int row  = (blockIdx.x - 512) * 4 + wv;  // 0..4095  (b*1024 + q)
        const float4* p = (const float4*)(attn + (size_t)row * NL_);

        float v0 = -FLT_MAX, v1 = -FLT_MAX;
        int   i0 = 0x7fffffff, i1 = 0x7fffffff;

        #pragma unroll
        for (int s = 0; s < 4; ++s) {
            float4 u = p[lane + 64 * s];
            int j = 4 * (lane + 64 * s);        // strictly increasing per lane
            float vals[4] = {u.x, u.y, u.z, u.w};
            #pragma unroll
            for (int t = 0; t < 4; ++t) {
                float a = vals[t];
                int   ji = j + t;
                if (a > v0)      { v1 = v0; i1 = i0; v0 = a; i0 = ji; }
                else if (a > v1) { v1 = a; i1 = ji; }
            }
        }

        #pragma unroll
        for (int off = 32; off >= 1; off >>= 1) {
            float ov0 = __shfl_xor(v0, off, 64);
            int   oi0 = __shfl_xor(i0, off, 64);
            float ov1 = __shfl_xor(v1, off, 64);
            int   oi1 = __shfl_xor(i1, off, 64);
            bool a_first = (v0 > ov0) || (v0 == ov0 && i0 < oi0);
            float n0, n1; int m0, m1;
            if (a_first) {
                n0 = v0; m0 = i0;
                bool s2 = (v1 > ov0) || (v1 == ov0 && i1 < oi0);
                n1 = s2 ? v1 : ov0; m1 = s2 ? i1 : oi0;
            } else {
                n0 = ov0; m0 = oi0;
                bool s2 = (v0 > ov1) || (v0 == ov1 && i0 < oi1);
                n1 = s2 ? v0 : ov1; m1 = s2 ? i0 : oi1;
            }
            v0 = n0; i0 = m0; v1 = n1; i1 = m1;
        }

        if (lane == 0) {
            float e  = expf(v1 - v0);            // v1 <= v0, safe
            float w0 = 1.f / (1.f + e);
            tmap[row] = make_int2(i0, i1);
            wmap[row] = make_float2(w0, 1.f - w0);
        }
    }
}

// ---------------------------------------------------------------------------
// Kernel B: combine + write. Output constant over each 4x4 tile -> one value
// per thread, broadcast into a 16B store. With S_t[b][c][cell] layout, the
// whole block's gathers live in one 4KB slice (L1-resident after first touch).
// ---------------------------------------------------------------------------
__global__ __launch_bounds__(256) void k_out(const float* __restrict__ S,
                                             const int2* __restrict__ tmap,
                                             const float2* __restrict__ wmap,
                                             float* __restrict__ out) {
    int tid = blockIdx.x * 256 + threadIdx.x;   // 0 .. 2*1024*1024-1
    int wb = tid & 31;            // cell column
    int h  = (tid >> 5) & 127;    // output row
    int c  = (tid >> 12) & 127;
    int b  = tid >> 19;
    int q  = (h >> 2) * WL_ + wb;
    int row = b * NL_ + q;

    int2   t = tmap[row];
    float2 w = wmap[row];
    const float* Sp = S + ((size_t)(b * C_ + c)) * NL_;   // 4KB slice
    float s0 = Sp[t.x];
    float s1 = Sp[t.y];
    float val = (w.x * s0 + w.y * s1) * 0.0625f;   // /16

    float4 o4 = make_float4(val, val, val, val);
    *(float4*)(out + ((size_t)(b * C_ + c) * H_ + h) * W_ + wb * 4) = o4;
}

extern "C" void kernel_launch(void* const* d_in, const int* in_sizes, int n_in,
                              void* d_out, int out_size, void* d_ws, size_t ws_size,
                              hipStream_t stream) {
    const float* v    = (const float*)d_in[0];   // fp32 (B,C,H,W)
    const float* attn = (const float*)d_in[1];   // fp32 (B,1024,1024)
    float* out = (float*)d_out;                  // fp32 (B,C,H,W)

    char* base = (char*)d_ws;
    float*  S    = (float*)base;                                   // 2 MB, S_t[b][c][cell]
    int2*   tmap = (int2*)(base + (size_t)B_ * C_ * NL_ * 4);      // 32 KB
    float2* wmap = (float2*)(base + (size_t)B_ * C_ * NL_ * 4 + 4096 * sizeof(int2));

    k_fusedA<<<512 + 1024, 256, 0, stream>>>(v, attn, S, tmap, wmap);
    k_out<<<(B_ * C_ * H_ * WL_) / 256, 256, 0, stream>>>(S, tmap, wmap, out);
}

// Round 5
// 97.629 us; speedup vs baseline: 1.1331x; 1.0345x over previous
//
#include <hip/hip_runtime.h>
#include <float.h>

#define B_ 4
#define C_ 128
#define H_ 128
#define W_ 128
#define WL_ 32
#define NL_ 1024   // 32*32 low-res cells

// ---------------------------------------------------------------------------
// Kernel A: fused block-sum + top-2 (grid sections).
//   blocks [0, 512):    4x4 block sums -> S_t[b][c][cell]  (coalesced writes)
//   blocks [512, 1536): stable top-2 + 2-way softmax per attention row
// ---------------------------------------------------------------------------
__global__ __launch_bounds__(256) void k_fusedA(const float* __restrict__ v,
                                                const float* __restrict__ attn,
                                                float* __restrict__ S,
                                                int2* __restrict__ tmap,
                                                float2* __restrict__ wmap) {
    if (blockIdx.x < 512) {
        int plane = blockIdx.x;          // b*C + c
        const float* vp = v + (size_t)plane * (H_ * W_);
        float* Sp = S + (size_t)plane * NL_;
        int tid = threadIdx.x;
        #pragma unroll
        for (int rep = 0; rep < 4; ++rep) {
            int cell = rep * 256 + tid;          // 0..1023
            int cr = cell >> 5, cc = cell & 31;
            const float* rp = vp + (cr * 4) * W_ + cc * 4;
            float s = 0.f;
            #pragma unroll
            for (int r = 0; r < 4; ++r) {
                float4 u = *(const float4*)(rp + r * W_);
                s += u.x + u.y + u.z + u.w;
            }
            Sp[cell] = s;                        // coalesced: lanes -> cells
        }
    } else {
        // stable top-2 for one attention row per wave
        int lane = threadIdx.x & 63;
        int wv   = threadIdx.x >> 6;
        int row  = (blockIdx.x - 512) * 4 + wv;  // 0..4095 (b*1024 + q)
        const float4* p = (const float4*)(attn + (size_t)row * NL_);

        float v0 = -FLT_MAX, v1 = -FLT_MAX;
        int   i0 = 0x7fffffff, i1 = 0x7fffffff;

        #pragma unroll
        for (int s = 0; s < 4; ++s) {
            float4 u = p[lane + 64 * s];
            int j = 4 * (lane + 64 * s);        // strictly increasing per lane
            float vals[4] = {u.x, u.y, u.z, u.w};
            #pragma unroll
            for (int t = 0; t < 4; ++t) {
                float a = vals[t];
                int   ji = j + t;
                if (a > v0)      { v1 = v0; i1 = i0; v0 = a; i0 = ji; }
                else if (a > v1) { v1 = a; i1 = ji; }
            }
        }

        #pragma unroll
        for (int off = 32; off >= 1; off >>= 1) {
            float ov0 = __shfl_xor(v0, off, 64);
            int   oi0 = __shfl_xor(i0, off, 64);
            float ov1 = __shfl_xor(v1, off, 64);
            int   oi1 = __shfl_xor(i1, off, 64);
            bool a_first = (v0 > ov0) || (v0 == ov0 && i0 < oi0);
            float n0, n1; int m0, m1;
            if (a_first) {
                n0 = v0; m0 = i0;
                bool s2 = (v1 > ov0) || (v1 == ov0 && i1 < oi0);
                n1 = s2 ? v1 : ov0; m1 = s2 ? i1 : oi0;
            } else {
                n0 = ov0; m0 = oi0;
                bool s2 = (v0 > ov1) || (v0 == ov1 && i0 < oi1);
                n1 = s2 ? v0 : ov1; m1 = s2 ? i0 : oi1;
            }
            v0 = n0; i0 = m0; v1 = n1; i1 = m1;
        }

        if (lane == 0) {
            float e  = expf(v1 - v0);            // v1 <= v0, safe
            float w0 = 1.f / (1.f + e);
            tmap[row] = make_int2(i0, i1);
            wmap[row] = make_float2(w0, 1.f - w0);
        }
    }
}

// ---------------------------------------------------------------------------
// Kernel B: combine + write. One thread per 4x4-tile value: compute once,
// store all 4 rows (4 x 16B). Quarter the gathers/index math of the per-row
// version. Wave writes two full 512B output rows per store instruction.
// ---------------------------------------------------------------------------
__global__ __launch_bounds__(256) void k_out(const float* __restrict__ S,
                                             const int2* __restrict__ tmap,
                                             const float2* __restrict__ wmap,
                                             float* __restrict__ out) {
    int item = blockIdx.x * 256 + threadIdx.x;   // 0..524287
    int wb = item & 31;           // cell column
    int ht = (item >> 5) & 31;    // tile row (h/4)
    int c  = (item >> 10) & 127;
    int b  = item >> 17;
    int row = b * NL_ + ht * WL_ + wb;

    int2   t = tmap[row];
    float2 w = wmap[row];
    const float* Sp = S + ((size_t)(b * C_ + c)) * NL_;   // 4KB slice, L1-resident
    float val = (w.x * Sp[t.x] + w.y * Sp[t.y]) * 0.0625f;

    float4 o4 = make_float4(val, val, val, val);
    float* op = out + ((size_t)(b * C_ + c) * H_ + ht * 4) * W_ + wb * 4;
    #pragma unroll
    for (int r = 0; r < 4; ++r)
        *(float4*)(op + r * W_) = o4;            // 4 rows of the 4x4 tile
}

extern "C" void kernel_launch(void* const* d_in, const int* in_sizes, int n_in,
                              void* d_out, int out_size, void* d_ws, size_t ws_size,
                              hipStream_t stream) {
    const float* v    = (const float*)d_in[0];   // fp32 (B,C,H,W)
    const float* attn = (const float*)d_in[1];   // fp32 (B,1024,1024)
    float* out = (float*)d_out;                  // fp32 (B,C,H,W)

    char* base = (char*)d_ws;
    float*  S    = (float*)base;                                   // 2 MB, S_t[b][c][cell]
    int2*   tmap = (int2*)(base + (size_t)B_ * C_ * NL_ * 4);      // 32 KB
    float2* wmap = (float2*)(base + (size_t)B_ * C_ * NL_ * 4 + 4096 * sizeof(int2));

    k_fusedA<<<512 + 1024, 256, 0, stream>>>(v, attn, S, tmap, wmap);
    k_out<<<(B_ * C_ * WL_ * WL_) / 256, 256, 0, stream>>>(S, tmap, wmap, out);
}